// Round 7
// baseline (34789.886 us; speedup 1.0000x reference)
//
#include <hip/hip_runtime.h>
#include <hip/hip_bf16.h>
#include <cmath>

#define DEVI __device__ __forceinline__

constexpr int B_   = 4;
constexpr int M_   = 2048;
constexpr int C_   = 256;
constexpr int H_   = 4;
constexpr int HD_  = 64;
constexpr int L_   = 9;
constexpr int TOK_ = B_ * M_;     // 8192
constexpr int C2_  = 2 * C_;      // 512
constexpr int C3_  = 3 * C_;      // 768
constexpr int NS_  = 2049;        // scores dim

// ---------------------------------------------------------------- helpers
DEVI float logsig_f(float x) {
  if (x >= 0.0f) return -log1pf(__expf(-x));
  return x - log1pf(__expf(x));
}

DEVI float gelu_tanh(float x) {
  float x3 = x * x * x;
  float t = tanhf(0.7978845608028654f * (x + 0.044715f * x3));
  return 0.5f * x * (1.0f + t);
}

// ---------------------------------------------------------------- posenc (compact: 32 cos + 32 sin per token)
__global__ void posenc_kernel(const float* __restrict__ kpts, const float* __restrict__ wh,
                              const float* __restrict__ Wr, float* __restrict__ cc,
                              float* __restrict__ sc) {
  int idx = blockIdx.x * blockDim.x + threadIdx.x;   // B*M*32
  if (idx >= B_ * M_ * 32) return;
  int j  = idx & 31;
  int bm = idx >> 5;
  float w = wh[0], h = wh[1];
  float smax = fmaxf(w, h) * 0.5f;
  float kx = (kpts[bm * 2 + 0] - w * 0.5f) / smax;
  float ky = (kpts[bm * 2 + 1] - h * 0.5f) / smax;
  float p = kx * Wr[j] + ky * Wr[32 + j];
  cc[bm * 32 + j] = cosf(p);
  sc[bm * 32 + j] = sinf(p);
}

// ---------------------------------------------------------------- generic fp32 GEMM
__global__ __launch_bounds__(256) void gemm_kernel(const float* __restrict__ A,
                                                   const float* __restrict__ W,
                                                   const float* __restrict__ bias,
                                                   const float* __restrict__ res,
                                                   float* __restrict__ out,
                                                   int K, int N, float oscale) {
  __shared__ alignas(16) float As[16][68];
  __shared__ alignas(16) float Ws[16][64];
  int tid = threadIdx.x;
  int rowBase = blockIdx.y << 6;
  int colBase = blockIdx.x << 6;
  int ty = tid >> 4, tx = tid & 15;
  float acc[4][4] = {};
  for (int k0 = 0; k0 < K; k0 += 16) {
#pragma unroll
    for (int i = 0; i < 4; i++) {
      int idx = tid + (i << 8);
      int r = idx >> 4, kk = idx & 15;
      As[kk][r] = A[(size_t)(rowBase + r) * K + (k0 + kk)];
      int kk2 = idx >> 6, cco = idx & 63;
      Ws[kk2][cco] = W[(size_t)(k0 + kk2) * N + colBase + cco];
    }
    __syncthreads();
#pragma unroll
    for (int kk = 0; kk < 16; kk++) {
      float4 a4 = *(const float4*)&As[kk][ty << 2];
      float4 b4 = *(const float4*)&Ws[kk][tx << 2];
      float a[4] = {a4.x, a4.y, a4.z, a4.w};
      float b[4] = {b4.x, b4.y, b4.z, b4.w};
#pragma unroll
      for (int i = 0; i < 4; i++)
#pragma unroll
        for (int j = 0; j < 4; j++) acc[i][j] += a[i] * b[j];
    }
    __syncthreads();
  }
#pragma unroll
  for (int i = 0; i < 4; i++) {
    int rr = rowBase + (ty << 2) + i;
#pragma unroll
    for (int j = 0; j < 4; j++) {
      int cco = colBase + (tx << 2) + j;
      float v = (acc[i][j] + bias[cco]) * oscale;
      if (res) v += res[(size_t)rr * N + cco];
      out[(size_t)rr * N + cco] = v;
    }
  }
}

// ---------------------------------------------------------------- fused [X,MSG]@W1 + b1 (K=512, N=512)
__global__ __launch_bounds__(256) void gemm_cat_kernel(const float* __restrict__ A1,
                                                       const float* __restrict__ A2,
                                                       const float* __restrict__ W,
                                                       const float* __restrict__ bias,
                                                       float* __restrict__ out) {
  __shared__ alignas(16) float As[16][68];
  __shared__ alignas(16) float Ws[16][64];
  int tid = threadIdx.x;
  int rowBase = blockIdx.y << 6;
  int colBase = blockIdx.x << 6;
  int ty = tid >> 4, tx = tid & 15;
  float acc[4][4] = {};
  for (int k0 = 0; k0 < C2_; k0 += 16) {
    const float* Asrc = (k0 < C_) ? (A1 + k0) : (A2 + (k0 - C_));
#pragma unroll
    for (int i = 0; i < 4; i++) {
      int idx = tid + (i << 8);
      int r = idx >> 4, kk = idx & 15;
      As[kk][r] = Asrc[(size_t)(rowBase + r) * C_ + kk];
      int kk2 = idx >> 6, cco = idx & 63;
      Ws[kk2][cco] = W[(size_t)(k0 + kk2) * C2_ + colBase + cco];
    }
    __syncthreads();
#pragma unroll
    for (int kk = 0; kk < 16; kk++) {
      float4 a4 = *(const float4*)&As[kk][ty << 2];
      float4 b4 = *(const float4*)&Ws[kk][tx << 2];
      float a[4] = {a4.x, a4.y, a4.z, a4.w};
      float b[4] = {b4.x, b4.y, b4.z, b4.w};
#pragma unroll
      for (int i = 0; i < 4; i++)
#pragma unroll
        for (int j = 0; j < 4; j++) acc[i][j] += a[i] * b[j];
    }
    __syncthreads();
  }
#pragma unroll
  for (int i = 0; i < 4; i++) {
    int rr = rowBase + (ty << 2) + i;
#pragma unroll
    for (int j = 0; j < 4; j++) {
      int cco = colBase + (tx << 2) + j;
      out[(size_t)rr * C2_ + cco] = acc[i][j] + bias[cco];
    }
  }
}

// ---------------------------------------------------------------- fused flash attention
__global__ __launch_bounds__(256) void flash_kernel(const float* __restrict__ Qb,
                                                    const float* __restrict__ Kb,
                                                    const float* __restrict__ Vb,
                                                    int ld, int qcol, int kcol, int vcol,
                                                    const float* __restrict__ cc,
                                                    const float* __restrict__ sc,
                                                    float* __restrict__ O, float scale) {
  __shared__ alignas(16) float Ks[64][68];
  __shared__ alignas(16) float Vs[64][68];
  __shared__ alignas(16) float Ps[64][68];
  int bh = blockIdx.y;
  int b = bh >> 2, h = bh & 3;
  int mBase = blockIdx.x * 64;
  size_t tokbase = (size_t)b * M_;
  const float* Qp = Qb + tokbase * ld + qcol + h * 64;
  const float* Kp = Kb + tokbase * ld + kcol + h * 64;
  const float* Vp = Vb + tokbase * ld + vcol + h * 64;
  const float* ccb = cc ? cc + tokbase * 32 : nullptr;
  const float* scb = sc ? sc + tokbase * 32 : nullptr;
  int tid = threadIdx.x;
  int r = tid >> 2, cq = tid & 3;

  float qreg[64];
  {
    int m = mBase + r;
    const float* qrow = Qp + (size_t)m * ld;
#pragma unroll
    for (int i = 0; i < 16; i++) {
      float4 t4 = *(const float4*)(qrow + 4 * i);
      if (ccb) {
        float2 c2 = *(const float2*)(ccb + (size_t)m * 32 + 2 * i);
        float2 s2 = *(const float2*)(scb + (size_t)m * 32 + 2 * i);
        float x0 = t4.x * c2.x - t4.y * s2.x;
        float y0 = t4.y * c2.x + t4.x * s2.x;
        float z0 = t4.z * c2.y - t4.w * s2.y;
        float w0 = t4.w * c2.y + t4.z * s2.y;
        t4 = make_float4(x0, y0, z0, w0);
      }
      qreg[4 * i] = t4.x; qreg[4 * i + 1] = t4.y;
      qreg[4 * i + 2] = t4.z; qreg[4 * i + 3] = t4.w;
    }
  }

  float m_run = -INFINITY, l_run = 0.0f;
  float acc[16];
#pragma unroll
  for (int i = 0; i < 16; i++) acc[i] = 0.0f;

  for (int t0 = 0; t0 < M_; t0 += 64) {
    __syncthreads();
#pragma unroll
    for (int i = 0; i < 4; i++) {
      int idx = tid + (i << 8);
      int rr = idx >> 4, dd = (idx & 15) << 2;
      int tok = t0 + rr;
      float4 kv = *(const float4*)(Kp + (size_t)tok * ld + dd);
      if (ccb) {
        float2 c2 = *(const float2*)(ccb + (size_t)tok * 32 + (dd >> 1));
        float2 s2 = *(const float2*)(scb + (size_t)tok * 32 + (dd >> 1));
        float x0 = kv.x * c2.x - kv.y * s2.x;
        float y0 = kv.y * c2.x + kv.x * s2.x;
        float z0 = kv.z * c2.y - kv.w * s2.y;
        float w0 = kv.w * c2.y + kv.z * s2.y;
        kv = make_float4(x0, y0, z0, w0);
      }
      *(float4*)&Ks[rr][dd] = kv;
      *(float4*)&Vs[rr][dd] = *(const float4*)(Vp + (size_t)tok * ld + dd);
    }
    __syncthreads();

    float sv[16];
#pragma unroll
    for (int jj = 0; jj < 16; jj++) {
      int j = cq * 16 + jj;
      const float4* krow = (const float4*)&Ks[j][0];
      float s = 0.0f;
#pragma unroll
      for (int d4 = 0; d4 < 16; d4++) {
        float4 kv = krow[d4];
        s += qreg[4 * d4] * kv.x + qreg[4 * d4 + 1] * kv.y +
             qreg[4 * d4 + 2] * kv.z + qreg[4 * d4 + 3] * kv.w;
      }
      sv[jj] = s * scale;
    }

    float mx = sv[0];
#pragma unroll
    for (int jj = 1; jj < 16; jj++) mx = fmaxf(mx, sv[jj]);
    mx = fmaxf(mx, __shfl_xor(mx, 1));
    mx = fmaxf(mx, __shfl_xor(mx, 2));
    float m_new = fmaxf(m_run, mx);
    float alpha = __expf(m_run - m_new);
    float lsum = 0.0f;
#pragma unroll
    for (int jj = 0; jj < 16; jj++) { sv[jj] = __expf(sv[jj] - m_new); lsum += sv[jj]; }
    lsum += __shfl_xor(lsum, 1);
    lsum += __shfl_xor(lsum, 2);
    l_run = l_run * alpha + lsum;
    m_run = m_new;
#pragma unroll
    for (int jj = 0; jj < 16; jj++) Ps[r][cq * 16 + jj] = sv[jj];
#pragma unroll
    for (int i = 0; i < 16; i++) acc[i] *= alpha;
    __syncthreads();

#pragma unroll 4
    for (int j = 0; j < 64; j++) {
      float p = Ps[r][j];
      const float4* vrow = (const float4*)&Vs[j][cq * 16];
#pragma unroll
      for (int i4 = 0; i4 < 4; i4++) {
        float4 vv = vrow[i4];
        acc[4 * i4]     += p * vv.x;
        acc[4 * i4 + 1] += p * vv.y;
        acc[4 * i4 + 2] += p * vv.z;
        acc[4 * i4 + 3] += p * vv.w;
      }
    }
  }

  float inv = 1.0f / l_run;
  float* Op = O + (tokbase + mBase + r) * C_ + h * 64 + cq * 16;
#pragma unroll
  for (int i = 0; i < 16; i++) Op[i] = acc[i] * inv;
}

// ---------------------------------------------------------------- LayerNorm + GELU
__global__ __launch_bounds__(256) void ln_gelu_kernel(float* __restrict__ h,
                                                      const float* __restrict__ g,
                                                      const float* __restrict__ beta) {
  __shared__ float red[4];
  int t = blockIdx.x, tid = threadIdx.x;
  float* hr = h + (size_t)t * C2_;
  float a = hr[tid], b2 = hr[tid + 256];
  float s = a + b2;
  for (int o = 1; o < 64; o <<= 1) s += __shfl_xor(s, o);
  if ((tid & 63) == 0) red[tid >> 6] = s;
  __syncthreads();
  float mu = (red[0] + red[1] + red[2] + red[3]) * (1.0f / 512.0f);
  __syncthreads();
  float da = a - mu, db = b2 - mu;
  s = da * da + db * db;
  for (int o = 1; o < 64; o <<= 1) s += __shfl_xor(s, o);
  if ((tid & 63) == 0) red[tid >> 6] = s;
  __syncthreads();
  float var = (red[0] + red[1] + red[2] + red[3]) * (1.0f / 512.0f);
  float rs = rsqrtf(var + 1e-5f);
  float xa = da * rs * g[tid] + beta[tid];
  float xb = db * rs * g[tid + 256] + beta[tid + 256];
  hr[tid]       = gelu_tanh(xa);
  hr[tid + 256] = gelu_tanh(xb);
}

// ---------------------------------------------------------------- z = d @ match_w + b, log_sigmoid(+/-)
__global__ __launch_bounds__(256) void z_kernel(const float* __restrict__ d,
                                                const float* __restrict__ mw,
                                                const float* __restrict__ mb,
                                                float* __restrict__ ls,
                                                float* __restrict__ lsn) {
  int row = blockIdx.x * 4 + (threadIdx.x >> 6);
  int lane = threadIdx.x & 63;
  const float4* dr = (const float4*)(d + (size_t)row * C_);
  float4 v = dr[lane];
  float4 w4 = ((const float4*)mw)[lane];
  float s = v.x * w4.x + v.y * w4.y + v.z * w4.z + v.w * w4.w;
  for (int o = 1; o < 64; o <<= 1) s += __shfl_xor(s, o);
  if (lane == 0) {
    float zz = s + mb[0];
    ls[row]  = logsig_f(zz);
    lsn[row] = logsig_f(-zz);
  }
}

// ---------------------------------------------------------------- fused matching-head pass
// Recomputes sim tile-by-tile in fp32 from A (rows) and Bm (cols), per batch b.
// mode 0: row logsumexp(sim) -> lse_out
// mode 1: row argmax of (2*sim + addv[n]) -> am_out, max_out = best + rowv[row];
//         also writes scores f32(2*sim + rowv[row] + addv[n]) at stride NS_
// mode 2: row argmax of (2*sim + addv[n]) -> am_out only
__global__ __launch_bounds__(256) void head_kernel(const float* __restrict__ A,
                                                   const float* __restrict__ Bm,
                                                   const float* __restrict__ addv,
                                                   const float* __restrict__ rowv,
                                                   float* __restrict__ lse_out,
                                                   float* __restrict__ max_out,
                                                   int* __restrict__ am_out,
                                                   float* __restrict__ scores_out,
                                                   int mode) {
  __shared__ alignas(16) float As[16][68];
  __shared__ alignas(16) float Bs[16][68];
  int tid = threadIdx.x;
  int ty = tid >> 4, tx = tid & 15;
  int mBase = blockIdx.x << 6;
  int b = blockIdx.y;
  const float* Ab = A + (size_t)b * M_ * C_;
  const float* Bb = Bm + (size_t)b * M_ * C_;
  const float* addb = addv ? addv + (size_t)b * M_ : nullptr;
  const float* rowb = rowv ? rowv + (size_t)b * M_ : nullptr;

  float on_m[4], on_l[4], bst[4];
  int bidx[4];
#pragma unroll
  for (int i = 0; i < 4; i++) {
    on_m[i] = -INFINITY; on_l[i] = 0.0f; bst[i] = -INFINITY; bidx[i] = 0x7fffffff;
  }
  float rterm[4];
#pragma unroll
  for (int i = 0; i < 4; i++)
    rterm[i] = rowb ? rowb[mBase + (ty << 2) + i] : 0.0f;

  for (int nTile = 0; nTile < 32; nTile++) {
    int nBase = nTile << 6;
    float acc[4][4] = {};
    for (int k0 = 0; k0 < C_; k0 += 16) {
      __syncthreads();
#pragma unroll
      for (int i = 0; i < 4; i++) {
        int idx = tid + (i << 8);
        int r = idx >> 4, kk = idx & 15;
        As[kk][r] = Ab[(size_t)(mBase + r) * C_ + (k0 + kk)];
        Bs[kk][r] = Bb[(size_t)(nBase + r) * C_ + (k0 + kk)];
      }
      __syncthreads();
#pragma unroll
      for (int kk = 0; kk < 16; kk++) {
        float4 a4 = *(const float4*)&As[kk][ty << 2];
        float4 b4 = *(const float4*)&Bs[kk][tx << 2];
        float a[4] = {a4.x, a4.y, a4.z, a4.w};
        float bb[4] = {b4.x, b4.y, b4.z, b4.w};
#pragma unroll
        for (int i = 0; i < 4; i++)
#pragma unroll
          for (int j = 0; j < 4; j++) acc[i][j] += a[i] * bb[j];
      }
    }
    if (mode == 0) {
#pragma unroll
      for (int i = 0; i < 4; i++)
#pragma unroll
        for (int j = 0; j < 4; j++) {
          float s = acc[i][j];
          if (s > on_m[i]) {
            on_l[i] = on_l[i] * __expf(on_m[i] - s) + 1.0f;
            on_m[i] = s;
          } else {
            on_l[i] += __expf(s - on_m[i]);
          }
        }
    } else {
      float addn[4];
#pragma unroll
      for (int j = 0; j < 4; j++)
        addn[j] = addb ? addb[nBase + (tx << 2) + j] : 0.0f;
#pragma unroll
      for (int i = 0; i < 4; i++)
#pragma unroll
        for (int j = 0; j < 4; j++) {
          float v = 2.0f * acc[i][j] + addn[j];
          int n = nBase + (tx << 2) + j;
          if (v > bst[i]) { bst[i] = v; bidx[i] = n; }
        }
      if (mode == 1) {
#pragma unroll
        for (int i = 0; i < 4; i++) {
          size_t ro = ((size_t)(b * NS_ + mBase + (ty << 2) + i)) * NS_ + nBase + (tx << 2);
#pragma unroll
          for (int j = 0; j < 4; j++)
            scores_out[ro + j] = 2.0f * acc[i][j] + rterm[i] + addn[j];
        }
      }
    }
  }

  if (mode == 0) {
#pragma unroll
    for (int i = 0; i < 4; i++) {
      float Mv = on_m[i], Lv = on_l[i];
      for (int off = 1; off < 16; off <<= 1) {
        float M2 = __shfl_xor(Mv, off);
        float L2 = __shfl_xor(Lv, off);
        float Mn = fmaxf(Mv, M2);
        Lv = Lv * __expf(Mv - Mn) + L2 * __expf(M2 - Mn);
        Mv = Mn;
      }
      if (tx == 0) lse_out[(size_t)b * M_ + mBase + (ty << 2) + i] = Mv + logf(Lv);
    }
  } else {
#pragma unroll
    for (int i = 0; i < 4; i++) {
      float v = bst[i];
      int ix = bidx[i];
      for (int off = 1; off < 16; off <<= 1) {
        float v2 = __shfl_xor(v, off);
        int i2 = __shfl_xor(ix, off);
        if (v2 > v || (v2 == v && i2 < ix)) { v = v2; ix = i2; }
      }
      if (tx == 0) {
        size_t o = (size_t)b * M_ + mBase + (ty << 2) + i;
        am_out[o] = ix;
        if (mode == 1) max_out[o] = v + rterm[i];
      }
    }
  }
}

// ---------------------------------------------------------------- row/col additive terms
__global__ void rcterm_kernel(const float* __restrict__ ls0, const float* __restrict__ lse2,
                              const float* __restrict__ ls1, const float* __restrict__ lse1,
                              float* __restrict__ rt, float* __restrict__ ct) {
  int i = blockIdx.x * blockDim.x + threadIdx.x;
  if (i < B_ * M_) { rt[i] = ls0[i] - lse2[i]; ct[i] = ls1[i] - lse1[i]; }
}

// ---------------------------------------------------------------- scores edges (col N, row M, corner), fp32
__global__ void edge_kernel(const float* __restrict__ lsn0, const float* __restrict__ lsn1,
                            float* __restrict__ sco) {
  int i = blockIdx.x * blockDim.x + threadIdx.x;   // B*2048
  if (i >= B_ * M_) return;
  int b = i >> 11, t = i & 2047;
  sco[((size_t)b * NS_ + t) * NS_ + 2048] = lsn0[i];
  sco[((size_t)b * NS_ + 2048) * NS_ + t] = lsn1[i];
  if (t == 0) sco[((size_t)b * NS_ + 2048) * NS_ + 2048] = 0.0f;
}

// ---------------------------------------------------------------- mscores0 / valid0 (workspace)
__global__ void match0ws_kernel(const int* __restrict__ am0, const int* __restrict__ am1,
                                const float* __restrict__ max0, float* __restrict__ ms0f,
                                int* __restrict__ val0) {
  int i = blockIdx.x * blockDim.x + threadIdx.x;
  if (i >= B_ * M_) return;
  int b = i >> 11, m = i & 2047;
  int a0 = am0[i];
  bool mutual = (am1[b * M_ + a0] == m);
  float ms = mutual ? __expf(max0[i]) : 0.0f;
  ms0f[i] = ms;
  val0[i] = (mutual && ms > 0.1f) ? 1 : 0;
}

// ---------------------------------------------------------------- final small outputs, FP32, runs last
__global__ void finalout_kernel(const int* __restrict__ am0, const int* __restrict__ am1,
                                const float* __restrict__ ms0f, const int* __restrict__ val0,
                                float* __restrict__ out) {
  int i = blockIdx.x * blockDim.x + threadIdx.x;
  if (i >= B_ * M_) return;
  int b = i >> 11, t = i & 2047;
  // image-0 side
  int a0 = am0[i];
  bool mut0 = (am1[b * M_ + a0] == t);
  float ms0 = ms0f[i];
  bool v0 = mut0 && (ms0 > 0.1f);
  out[i] = v0 ? (float)a0 : -1.0f;                  // m0
  out[2 * B_ * M_ + i] = ms0;                       // mscores0
  // image-1 side
  int a1 = am1[i];
  bool mut1 = (am0[b * M_ + a1] == t);
  float ms1 = mut1 ? ms0f[b * M_ + a1] : 0.0f;
  bool v1 = mut1 && (val0[b * M_ + a1] != 0);
  out[B_ * M_ + i] = v1 ? (float)a1 : -1.0f;        // m1
  out[3 * B_ * M_ + i] = ms1;                       // mscores1
}

// ================================================================ host
extern "C" void kernel_launch(void* const* d_in, const int* in_sizes, int n_in,
                              void* d_out, int out_size, void* d_ws, size_t ws_size,
                              hipStream_t stream) {
  const float* kpts0      = (const float*)d_in[0];
  const float* desc0      = (const float*)d_in[1];
  const float* kpts1      = (const float*)d_in[2];
  const float* desc1      = (const float*)d_in[3];
  const float* image_size = (const float*)d_in[4];
  const float* Wr         = (const float*)d_in[5];
  const float* saqkv_W    = (const float*)d_in[6];
  const float* saqkv_b    = (const float*)d_in[7];
  const float* saout_W    = (const float*)d_in[8];
  const float* saout_b    = (const float*)d_in[9];
  const float* saff_W1    = (const float*)d_in[10];
  const float* saff_b1    = (const float*)d_in[11];
  const float* saff_g     = (const float*)d_in[12];
  const float* saff_beta  = (const float*)d_in[13];
  const float* saff_W2    = (const float*)d_in[14];
  const float* saff_b2    = (const float*)d_in[15];
  const float* caqk_W     = (const float*)d_in[16];
  const float* caqk_b     = (const float*)d_in[17];
  const float* cav_W      = (const float*)d_in[18];
  const float* cav_b      = (const float*)d_in[19];
  const float* caout_W    = (const float*)d_in[20];
  const float* caout_b    = (const float*)d_in[21];
  const float* caff_W1    = (const float*)d_in[22];
  const float* caff_b1    = (const float*)d_in[23];
  const float* caff_g     = (const float*)d_in[24];
  const float* caff_beta  = (const float*)d_in[25];
  const float* caff_W2    = (const float*)d_in[26];
  const float* caff_b2    = (const float*)d_in[27];
  const float* fproj_W    = (const float*)d_in[28];
  const float* fproj_b    = (const float*)d_in[29];
  const float* match_w    = (const float*)d_in[30];
  const float* match_b    = (const float*)d_in[31];

  // FP32 output layout (R0-R6 forensics: buffer is float32, not bf16):
  // m0@0, m1@8192, mscores0@16384, mscores1@24576, scores@32768
  float* ofp = (float*)d_out;
  float* SCO = ofp + 4 * B_ * M_;

  // ---------------- workspace layout: 7.5N floats ~ 63 MB
  constexpr size_t N = (size_t)TOK_ * C_;           // 2,097,152 floats
  constexpr size_t Qc = (size_t)B_ * M_ * 32;
  float* Wp  = (float*)d_ws;
  float* D0  = Wp;
  float* D1  = D0 + N;
  float* CC0 = D1 + N;
  float* SC0 = CC0 + Qc;
  float* CC1 = SC0 + Qc;
  float* SC1 = CC1 + Qc;
  float* S0  = SC1 + Qc;
  float* S1  = S0 + N;
  float* S2  = S1 + N;
  float* S3  = S2 + N;
  float* S4  = S3 + N;

  // small final-phase arrays live in S2 (free during final phase)
  float* LS0  = S2;
  float* LSN0 = LS0 + 8192;
  float* LS1  = LSN0 + 8192;
  float* LSN1 = LS1 + 8192;
  float* LSE2 = LSN1 + 8192;
  float* LSE1 = LSE2 + 8192;
  float* RT   = LSE1 + 8192;
  float* CT   = RT + 8192;
  float* MAX0 = CT + 8192;
  float* MS0F = MAX0 + 8192;
  int*   AM0  = (int*)(MS0F + 8192);
  int*   AM1  = AM0 + 8192;
  int*   VAL0 = AM1 + 8192;

  auto gemm = [&](const float* A, const float* Wt, const float* bias, const float* res,
                  float* out, int K, int Ncols, float oscale) {
    gemm_kernel<<<dim3(Ncols >> 6, TOK_ >> 6), 256, 0, stream>>>(A, Wt, bias, res, out, K, Ncols, oscale);
  };

  auto ffn = [&](float* X, const float* msg_tok, const float* W1, const float* b1,
                 const float* g, const float* be, const float* W2, const float* b2) {
    gemm_cat_kernel<<<dim3(C2_ >> 6, TOK_ >> 6), 256, 0, stream>>>(X, msg_tok, W1, b1, S0);
    ln_gelu_kernel<<<TOK_, 256, 0, stream>>>(S0, g, be);
    gemm(S0, W2, b2, X, X, C2_, C_, 1.0f);
  };

  auto self_block = [&](float* X, const float* cc, const float* sc, int l) {
    const float* Wqkv = saqkv_W + (size_t)l * C_ * C3_;
    const float* bqkv = saqkv_b + (size_t)l * C3_;
    const float* Wo   = saout_W + (size_t)l * C_ * C_;
    const float* bo   = saout_b + (size_t)l * C_;
    gemm(X, Wqkv, bqkv, nullptr, S0, C_, C3_, 1.0f);     // QKV in S0..S2
    flash_kernel<<<dim3(M_ / 64, B_ * H_), 256, 0, stream>>>(
        S0, S0, S0, C3_, 0, C_, C2_, cc, sc, S3, 0.125f);
    gemm(S3, Wo, bo, nullptr, S4, C_, C_, 1.0f);
    ffn(X, S4,
        saff_W1 + (size_t)l * C2_ * C2_, saff_b1 + (size_t)l * C2_,
        saff_g + (size_t)l * C2_, saff_beta + (size_t)l * C2_,
        saff_W2 + (size_t)l * C2_ * C_, saff_b2 + (size_t)l * C_);
  };

  auto cross_block = [&](int l) {
    const float* Wqk = caqk_W + (size_t)l * C_ * C_;
    const float* bqk = caqk_b + (size_t)l * C_;
    const float* Wv  = cav_W + (size_t)l * C_ * C_;
    const float* bv  = cav_b + (size_t)l * C_;
    const float* Wo  = caout_W + (size_t)l * C_ * C_;
    const float* bo  = caout_b + (size_t)l * C_;
    const float* W1  = caff_W1 + (size_t)l * C2_ * C2_;
    const float* b1  = caff_b1 + (size_t)l * C2_;
    const float* g   = caff_g + (size_t)l * C2_;
    const float* be  = caff_beta + (size_t)l * C2_;
    const float* W2  = caff_W2 + (size_t)l * C2_ * C_;
    const float* b2  = caff_b2 + (size_t)l * C_;
    gemm(D0, Wqk, bqk, nullptr, S0, C_, C_, 1.0f);
    gemm(D1, Wqk, bqk, nullptr, S1, C_, C_, 1.0f);
    gemm(D0, Wv, bv, nullptr, S2, C_, C_, 1.0f);
    gemm(D1, Wv, bv, nullptr, S3, C_, C_, 1.0f);
    flash_kernel<<<dim3(M_ / 64, B_ * H_), 256, 0, stream>>>(
        S0, S1, S3, C_, 0, 0, 0, nullptr, nullptr, S4, 0.125f);   // m0 -> S4
    flash_kernel<<<dim3(M_ / 64, B_ * H_), 256, 0, stream>>>(
        S1, S0, S2, C_, 0, 0, 0, nullptr, nullptr, S3, 0.125f);   // m1 -> S3
    gemm(S4, Wo, bo, nullptr, S2, C_, C_, 1.0f);     // ao0 -> S2
    gemm(S3, Wo, bo, nullptr, S4, C_, C_, 1.0f);     // ao1 -> S4
    ffn(D0, S2, W1, b1, g, be, W2, b2);
    ffn(D1, S4, W1, b1, g, be, W2, b2);
  };

  // ---------------- pipeline
  hipMemcpyAsync(D0, desc0, N * sizeof(float), hipMemcpyDeviceToDevice, stream);
  hipMemcpyAsync(D1, desc1, N * sizeof(float), hipMemcpyDeviceToDevice, stream);
  posenc_kernel<<<(B_ * M_ * 32 + 255) / 256, 256, 0, stream>>>(kpts0, image_size, Wr, CC0, SC0);
  posenc_kernel<<<(B_ * M_ * 32 + 255) / 256, 256, 0, stream>>>(kpts1, image_size, Wr, CC1, SC1);

  for (int l = 0; l < L_; l++) {
    self_block(D0, CC0, SC0, l);
    self_block(D1, CC1, SC1, l);
    cross_block(l);
  }

  // ---------------- final matching head (fp32 sim recomputed per pass)
  gemm(D0, fproj_W, fproj_b, nullptr, S0, C_, C_, 0.25f);   // md0
  gemm(D1, fproj_W, fproj_b, nullptr, S1, C_, C_, 0.25f);   // md1
  z_kernel<<<2048, 256, 0, stream>>>(D0, match_w, match_b, LS0, LSN0);
  z_kernel<<<2048, 256, 0, stream>>>(D1, match_w, match_b, LS1, LSN1);
  // pass 1: row lse (axis 2); pass 2: col lse (axis 1) via transpose swap
  head_kernel<<<dim3(32, B_), 256, 0, stream>>>(S0, S1, nullptr, nullptr,
                                                LSE2, nullptr, nullptr, nullptr, 0);
  head_kernel<<<dim3(32, B_), 256, 0, stream>>>(S1, S0, nullptr, nullptr,
                                                LSE1, nullptr, nullptr, nullptr, 0);
  rcterm_kernel<<<32, 256, 0, stream>>>(LS0, LSE2, LS1, LSE1, RT, CT);
  // pass 3: row argmax + max0 + inner scores (fp32); pass 4: col argmax
  head_kernel<<<dim3(32, B_), 256, 0, stream>>>(S0, S1, CT, RT,
                                                nullptr, MAX0, AM0, SCO, 1);
  head_kernel<<<dim3(32, B_), 256, 0, stream>>>(S1, S0, RT, nullptr,
                                                nullptr, nullptr, AM1, nullptr, 2);
  edge_kernel<<<32, 256, 0, stream>>>(LSN0, LSN1, SCO);
  match0ws_kernel<<<32, 256, 0, stream>>>(AM0, AM1, MAX0, MS0F, VAL0);
  finalout_kernel<<<32, 256, 0, stream>>>(AM0, AM1, MS0F, VAL0, ofp);

  (void)in_sizes; (void)n_in; (void)out_size; (void)ws_size;
}